// Round 1
// baseline (33.324 us; speedup 1.0000x reference)
//
#include <hip/hip_runtime.h>

// Reservoir sampling "add" — match JAX reference bit-exactly.
// Phase 1: memset winner[n] = -1 (0xFF).
// Phase 2: each sample k computes its target slot via threefry2x32
//          (partitionable mode, modern JAX default) and atomicMax's its
//          order index into winner[target].
// Phase 3: gather — out[s] = winner[s] >= 0 ? samples[winner[s]] : buffer[s].

#define D_FEAT 1024

#define ROTL32(x, r) (((x) << (r)) | ((x) >> (32 - (r))))

__device__ __forceinline__ void tf2x32(unsigned k0, unsigned k1,
                                       unsigned x0, unsigned x1,
                                       unsigned& o0, unsigned& o1) {
  const unsigned ks2 = k0 ^ k1 ^ 0x1BD11BDAu;
  x0 += k0; x1 += k1;
  // rounds [13,15,26,6]
  x0 += x1; x1 = ROTL32(x1, 13); x1 ^= x0;
  x0 += x1; x1 = ROTL32(x1, 15); x1 ^= x0;
  x0 += x1; x1 = ROTL32(x1, 26); x1 ^= x0;
  x0 += x1; x1 = ROTL32(x1, 6);  x1 ^= x0;
  x0 += k1; x1 += ks2 + 1u;
  // rounds [17,29,16,24]
  x0 += x1; x1 = ROTL32(x1, 17); x1 ^= x0;
  x0 += x1; x1 = ROTL32(x1, 29); x1 ^= x0;
  x0 += x1; x1 = ROTL32(x1, 16); x1 ^= x0;
  x0 += x1; x1 = ROTL32(x1, 24); x1 ^= x0;
  x0 += ks2; x1 += k0 + 2u;
  x0 += x1; x1 = ROTL32(x1, 13); x1 ^= x0;
  x0 += x1; x1 = ROTL32(x1, 15); x1 ^= x0;
  x0 += x1; x1 = ROTL32(x1, 26); x1 ^= x0;
  x0 += x1; x1 = ROTL32(x1, 6);  x1 ^= x0;
  x0 += k0; x1 += k1 + 3u;
  x0 += x1; x1 = ROTL32(x1, 17); x1 ^= x0;
  x0 += x1; x1 = ROTL32(x1, 29); x1 ^= x0;
  x0 += x1; x1 = ROTL32(x1, 16); x1 ^= x0;
  x0 += x1; x1 = ROTL32(x1, 24); x1 ^= x0;
  x0 += k1; x1 += ks2 + 4u;
  x0 += x1; x1 = ROTL32(x1, 13); x1 ^= x0;
  x0 += x1; x1 = ROTL32(x1, 15); x1 ^= x0;
  x0 += x1; x1 = ROTL32(x1, 26); x1 ^= x0;
  x0 += x1; x1 = ROTL32(x1, 6);  x1 ^= x0;
  x0 += ks2; x1 += k0 + 5u;
  o0 = x0; o1 = x1;
}

__global__ void winner_kernel(const int* __restrict__ i0p,
                              int* __restrict__ winner,
                              int N, int n) {
  int k = blockIdx.x * blockDim.x + threadIdx.x;
  if (k >= N) return;
  const int i0 = i0p[0];
  const int idx = i0 + k;
  int target;
  if (idx < n) {
    target = idx;  // fill phase
  } else {
    // Derive split subkeys from base key (0, 42) — jax.random.key(42).
    // Partitionable mode: k1 = tf(key,(0,0)), k2 = tf(key,(0,1)).
    // (All-constant args: compiler constant-folds these two calls.)
    unsigned k1a, k1b, k2a, k2b;
    tf2x32(0u, 42u, 0u, 0u, k1a, k1b);
    tf2x32(0u, 42u, 0u, 1u, k2a, k2b);
    // random_bits partitionable: bits[i] = xor of the two outputs of
    // tf(key, (hi64(i)=0, lo64(i)=i)).
    unsigned b1, b2;
    tf2x32(k1a, k1b, 0u, (unsigned)k, b1, b2);
    const unsigned hb = b1 ^ b2;
    tf2x32(k2a, k2b, 0u, (unsigned)k, b1, b2);
    const unsigned lb = b1 ^ b2;
    // randint combine (minval=0, maxval=idx+1): all uint32, no overflow
    // since span <= 65536.
    const unsigned span = (unsigned)(idx + 1);
    unsigned mult = 65536u % span;
    mult = (mult * mult) % span;
    const unsigned off = ((hb % span) * mult + (lb % span)) % span;
    if (off >= (unsigned)n) return;  // discarded
    target = (int)off;
  }
  atomicMax(&winner[target], k);
}

__global__ void gather_kernel(const float4* __restrict__ buf,
                              const float4* __restrict__ smp,
                              const int* __restrict__ winner,
                              float4* __restrict__ out) {
  const int D4 = D_FEAT / 4;  // 256 float4 per row
  const int s = blockIdx.x;
  const int w = winner[s];
  const float4* src = (w >= 0) ? (smp + (size_t)w * D4)
                               : (buf + (size_t)s * D4);
  out[(size_t)s * D4 + threadIdx.x] = src[threadIdx.x];
}

extern "C" void kernel_launch(void* const* d_in, const int* in_sizes, int n_in,
                              void* d_out, int out_size, void* d_ws, size_t ws_size,
                              hipStream_t stream) {
  const float* buffer  = (const float*)d_in[0];
  const float* samples = (const float*)d_in[1];
  const int*   i0p     = (const int*)d_in[2];
  float* out = (float*)d_out;

  const int n = out_size / D_FEAT;        // 16384 reservoir slots
  const int N = in_sizes[1] / D_FEAT;     // 65536 incoming samples

  int* winner = (int*)d_ws;
  hipMemsetAsync(winner, 0xFF, (size_t)n * sizeof(int), stream);  // -1

  winner_kernel<<<(N + 255) / 256, 256, 0, stream>>>(i0p, winner, N, n);

  gather_kernel<<<n, 256, 0, stream>>>((const float4*)buffer,
                                       (const float4*)samples,
                                       winner,
                                       (float4*)out);
}